// Round 3
// baseline (90854.395 us; speedup 1.0000x reference)
//
#include <hip/hip_runtime.h>

#define SEQ 32768
#define ISZ 256
#define HSZ 512
#define OSZ 256
#define GWG 8          // workgroups in recurrence (64 rows each)
#define RTHREADS 512   // 8 waves per WG

// ---------------------------------------------------------------------------
// Generic tiled GEMM:  C[M,N] = A[M,K] @ W[N,K]^T + bias[N]
// block = 256 threads, tile 64x64, TK=32, 4x4 outputs per thread.
// ---------------------------------------------------------------------------
__global__ __launch_bounds__(256) void gemm_bt_bias(
    const float* __restrict__ A, const float* __restrict__ W,
    const float* __restrict__ bias, float* __restrict__ C,
    int M, int N, int K)
{
  __shared__ float As[32][68];
  __shared__ float Bs[32][68];
  const int tx = threadIdx.x;
  const int tn = tx & 15, tm = tx >> 4;
  const int m0 = blockIdx.x * 64, n0 = blockIdx.y * 64;
  const int kl = tx & 31;   // k within tile
  const int rl = tx >> 5;   // row 0..7
  float acc[4][4] = {};

  for (int kt = 0; kt < K; kt += 32) {
#pragma unroll
    for (int i = 0; i < 8; ++i) {
      int m = rl + i * 8;
      As[kl][m] = A[(size_t)(m0 + m) * K + kt + kl];
      Bs[kl][m] = W[(size_t)(n0 + m) * K + kt + kl];
    }
    __syncthreads();
#pragma unroll
    for (int k = 0; k < 32; ++k) {
      float a[4], b[4];
#pragma unroll
      for (int i = 0; i < 4; ++i) a[i] = As[k][tm * 4 + i];
#pragma unroll
      for (int j = 0; j < 4; ++j) b[j] = Bs[k][tn * 4 + j];
#pragma unroll
      for (int i = 0; i < 4; ++i)
#pragma unroll
        for (int j = 0; j < 4; ++j)
          acc[i][j] = fmaf(a[i], b[j], acc[i][j]);
    }
    __syncthreads();
  }
#pragma unroll
  for (int i = 0; i < 4; ++i) {
    int m = m0 + tm * 4 + i;
#pragma unroll
    for (int j = 0; j < 4; ++j) {
      int n = n0 + tn * 4 + j;
      C[(size_t)m * N + n] = acc[i][j] + bias[n];
    }
  }
}

// ---------------------------------------------------------------------------
// Persistent recurrence: h_{t+1} = tanh(P[t] + Wh @ h_t)
// 8 WGs x 512 threads. WG g owns rows [64g, 64g+64). Wave w handles k-chunk
// [64w, 64w+64) — exactly WG w's published slice, so each wave spins on one
// per-step flag. Weights live in 64 VGPRs per lane.
//
// VGPR-residency: rounds 1-2 showed VGPR_Count=44 — the compiler
// REMATERIALIZED the loop-invariant Wh loads into the loop body (re-loading
// 128 KB/WG from L2 every step -> 87.5 ms). The empty asm "+v" barrier below
// makes the loaded values opaque (non-rematerializable), forcing them to stay
// live in VGPRs. __launch_bounds__(512,2) grants the 256-VGPR/wave budget.
// ---------------------------------------------------------------------------
__global__ __launch_bounds__(RTHREADS, 2) void rnn_recur(
    const float* __restrict__ P,     // [SEQ][HSZ]  (Wx@x_t + bh)
    const float* __restrict__ Wh,    // [HSZ][HSZ]
    float* __restrict__ h_hist,      // [SEQ+1][HSZ], row 0 pre-zeroed
    int* __restrict__ flags)         // [(SEQ+1)*GWG], pre-zeroed
{
  const int g = blockIdx.x;
  const int tid = threadIdx.x;
  const int w = tid >> 6;          // wave index = k-chunk index
  const int l = tid & 63;          // lane = row within WG slice
  const int row = (g << 6) + l;
  const int kbase = w << 6;

  // This lane's 64 weights: Wh[row][kbase .. kbase+64) as 16 x float4,
  // pinned into VGPRs via the asm value barrier.
  float4 wreg[16];
  {
    const float4* wsrc = (const float4*)(Wh + (size_t)row * HSZ + kbase);
#pragma unroll
    for (int j4 = 0; j4 < 16; ++j4) {
      float4 v = wsrc[j4];
      asm volatile("" : "+v"(v.x), "+v"(v.y), "+v"(v.z), "+v"(v.w));
      wreg[j4] = v;
    }
  }

  __shared__ float part[2][8][64];   // double-buffered partials -> 1 barrier/step

#define RL(v, ln) __uint_as_float(__builtin_amdgcn_readlane(__float_as_uint(v), (ln)))

  for (int t = 0; t < SEQ; ++t) {
    const int buf = t & 1;

    // Prefetch this step's P slice before spinning (hides HBM latency).
    float pv = 0.f;
    if (w == 0) pv = P[(size_t)t * HSZ + (g << 6) + l];

    if (t > 0) {
      if (l == 0) {
        while (__hip_atomic_load(&flags[t * GWG + w], __ATOMIC_RELAXED,
                                 __HIP_MEMORY_SCOPE_AGENT) == 0) { }
      }
      __builtin_amdgcn_fence(__ATOMIC_ACQUIRE, "agent");
    }

    // Coalesced load of this wave's h chunk (lane l -> element l).
    float vh = h_hist[(size_t)t * HSZ + kbase + l];

    // Partial dot: broadcast h[j] across the wave via readlane.
    float acc = 0.f;
#pragma unroll
    for (int j4 = 0; j4 < 16; ++j4) {
      float4 wv = wreg[j4];
      acc = fmaf(wv.x, RL(vh, 4 * j4 + 0), acc);
      acc = fmaf(wv.y, RL(vh, 4 * j4 + 1), acc);
      acc = fmaf(wv.z, RL(vh, 4 * j4 + 2), acc);
      acc = fmaf(wv.w, RL(vh, 4 * j4 + 3), acc);
    }
    part[buf][w][l] = acc;
    __syncthreads();

    if (w == 0) {
      float s = 0.f;
#pragma unroll
      for (int q = 0; q < 8; ++q) s += part[buf][q][l];
      float xv = s + pv;
      // fast tanh: 1 - 2/(e^{2x}+1), clamped
      xv = fminf(fmaxf(xv, -15.f), 15.f);
      float e = __expf(2.f * xv);
      float hn = 1.f - 2.f / (e + 1.f);
      h_hist[(size_t)(t + 1) * HSZ + (g << 6) + l] = hn;
      if (l == 0) {
        __hip_atomic_store(&flags[(t + 1) * GWG + g], 1, __ATOMIC_RELEASE,
                           __HIP_MEMORY_SCOPE_AGENT);
      }
    }
    // No trailing barrier: next step writes part[buf^1]; a wave can only pass
    // the NEXT barrier after wave 0 finished this reduce.
  }
#undef RL
}

// ---------------------------------------------------------------------------
extern "C" void kernel_launch(void* const* d_in, const int* in_sizes, int n_in,
                              void* d_out, int out_size, void* d_ws, size_t ws_size,
                              hipStream_t stream) {
  const float* x  = (const float*)d_in[0];  // [SEQ][ISZ]
  const float* Wx = (const float*)d_in[1];  // [HSZ][ISZ]
  const float* Wh = (const float*)d_in[2];  // [HSZ][HSZ]
  const float* Wy = (const float*)d_in[3];  // [OSZ][HSZ]
  const float* bh = (const float*)d_in[4];  // [HSZ]
  const float* by = (const float*)d_in[5];  // [OSZ]
  float* out = (float*)d_out;               // [SEQ][OSZ]

  float* P      = (float*)d_ws;                             // SEQ*HSZ      (64 MB)
  float* h_hist = P + (size_t)SEQ * HSZ;                    // (SEQ+1)*HSZ  (64 MB)
  int*   flags  = (int*)(h_hist + (size_t)(SEQ + 1) * HSZ); // (SEQ+1)*GWG  (1 MB)

  hipMemsetAsync(h_hist, 0, HSZ * sizeof(float), stream);                  // h_0 = 0
  hipMemsetAsync(flags, 0, (size_t)(SEQ + 1) * GWG * sizeof(int), stream); // no flag set

  // Phase 1: P = x @ Wx^T + bh
  gemm_bt_bias<<<dim3(SEQ / 64, HSZ / 64), dim3(256), 0, stream>>>(
      x, Wx, bh, P, SEQ, HSZ, ISZ);

  // Phase 2: sequential recurrence (persistent, 8 co-resident WGs)
  rnn_recur<<<dim3(GWG), dim3(RTHREADS), 0, stream>>>(P, Wh, h_hist, flags);

  // Phase 3: y = h_hist[1..] @ Wy^T + by
  gemm_bt_bias<<<dim3(SEQ / 64, OSZ / 64), dim3(256), 0, stream>>>(
      h_hist + HSZ, Wy, by, out, SEQ, OSZ, HSZ);
}

// Round 4
// 42081.226 us; speedup vs baseline: 2.1590x; 2.1590x over previous
//
#include <hip/hip_runtime.h>

#define SEQ 32768
#define ISZ 256
#define HSZ 512
#define OSZ 256
#define GWG 8          // workgroups in recurrence (64 rows each)
#define RTHREADS 512   // 8 waves per WG
#define SENT 0x7FAAAAAAu   // NaN sentinel: h = tanh(finite) is never NaN

// ---------------------------------------------------------------------------
// Generic tiled GEMM:  C[M,N] = A[M,K] @ W[N,K]^T + bias[N]
// ---------------------------------------------------------------------------
__global__ __launch_bounds__(256) void gemm_bt_bias(
    const float* __restrict__ A, const float* __restrict__ W,
    const float* __restrict__ bias, float* __restrict__ C,
    int M, int N, int K)
{
  __shared__ float As[32][68];
  __shared__ float Bs[32][68];
  const int tx = threadIdx.x;
  const int tn = tx & 15, tm = tx >> 4;
  const int m0 = blockIdx.x * 64, n0 = blockIdx.y * 64;
  const int kl = tx & 31;
  const int rl = tx >> 5;
  float acc[4][4] = {};

  for (int kt = 0; kt < K; kt += 32) {
#pragma unroll
    for (int i = 0; i < 8; ++i) {
      int m = rl + i * 8;
      As[kl][m] = A[(size_t)(m0 + m) * K + kt + kl];
      Bs[kl][m] = W[(size_t)(n0 + m) * K + kt + kl];
    }
    __syncthreads();
#pragma unroll
    for (int k = 0; k < 32; ++k) {
      float a[4], b[4];
#pragma unroll
      for (int i = 0; i < 4; ++i) a[i] = As[k][tm * 4 + i];
#pragma unroll
      for (int j = 0; j < 4; ++j) b[j] = Bs[k][tn * 4 + j];
#pragma unroll
      for (int i = 0; i < 4; ++i)
#pragma unroll
        for (int j = 0; j < 4; ++j)
          acc[i][j] = fmaf(a[i], b[j], acc[i][j]);
    }
    __syncthreads();
  }
#pragma unroll
  for (int i = 0; i < 4; ++i) {
    int m = m0 + tm * 4 + i;
#pragma unroll
    for (int j = 0; j < 4; ++j) {
      int n = n0 + tn * 4 + j;
      C[(size_t)m * N + n] = acc[i][j] + bias[n];
    }
  }
}

// ---------------------------------------------------------------------------
// Persistent recurrence: h_{t+1} = tanh(P[t] + Wh @ h_t)
//
// FENCE-FREE SYNC (round-4 redesign). Rounds 1-3 were all byte-identical at
// 87.5 ms regardless of weight handling -> bottleneck was the per-step
// agent-scope acquire/release fence pair (buffer_inv = full L2 invalidate +
// buffer_wbl2 writeback, every step, every WG; also evicted Wh from L2 each
// step). Now: NO fences, NO flags. h_hist[1..] is pre-filled with a NaN
// sentinel; producers publish h chunks with relaxed agent-scope atomic
// stores (write-through to L3); consumers poll the same addresses with
// relaxed agent-scope atomic loads (bypass L1/L2) until no lane sees the
// sentinel. The polled value IS the payload -> same-address atomic
// coherence is the only ordering required.
// ---------------------------------------------------------------------------
__global__ __launch_bounds__(RTHREADS, 2) void rnn_recur(
    const float* __restrict__ P,     // [SEQ][HSZ]  (Wx@x_t + bh)
    const float* __restrict__ Wh,    // [HSZ][HSZ]
    float* __restrict__ h_hist)      // [SEQ+1][HSZ]; row0=0, rows 1..=sentinel
{
  const int g = blockIdx.x;
  const int tid = threadIdx.x;
  const int w = tid >> 6;          // wave index = k-chunk index
  const int l = tid & 63;          // lane = row within WG slice
  const int row = (g << 6) + l;
  const int kbase = w << 6;

  // Lane's 64 weights as 16 x float4; asm value barrier discourages
  // rematerialization (and with fences gone, any re-load is L2-warm anyway).
  float4 wreg[16];
  {
    const float4* wsrc = (const float4*)(Wh + (size_t)row * HSZ + kbase);
#pragma unroll
    for (int j4 = 0; j4 < 16; ++j4) {
      float4 v = wsrc[j4];
      asm volatile("" : "+v"(v.x), "+v"(v.y), "+v"(v.z), "+v"(v.w));
      wreg[j4] = v;
    }
  }

  __shared__ float part[2][8][64];   // double-buffered partials -> 1 barrier/step

#define RL(v, ln) __uint_as_float(__builtin_amdgcn_readlane(__float_as_uint(v), (ln)))

  for (int t = 0; t < SEQ; ++t) {
    const int buf = t & 1;

    // Prefetch this step's P slice before polling (off critical path).
    float pv = 0.f;
    if (w == 0) pv = P[(size_t)t * HSZ + (g << 6) + l];

    // Poll-on-data: wait until this wave's h chunk is published (no sentinel
    // in any lane). Row 0 is pre-zeroed so t==0 needs no special case.
    float* hp = h_hist + (size_t)t * HSZ + kbase + l;
    float vh;
    do {
      vh = __hip_atomic_load(hp, __ATOMIC_RELAXED, __HIP_MEMORY_SCOPE_AGENT);
    } while (__any((int)(__float_as_uint(vh) == SENT)));

    // Partial dot: broadcast h[j] across the wave via readlane.
    // 4 independent accumulator chains (64-deep serial fma chain halved+).
    float a0 = 0.f, a1 = 0.f, a2 = 0.f, a3 = 0.f;
#pragma unroll
    for (int j4 = 0; j4 < 16; ++j4) {
      float4 wv = wreg[j4];
      a0 = fmaf(wv.x, RL(vh, 4 * j4 + 0), a0);
      a1 = fmaf(wv.y, RL(vh, 4 * j4 + 1), a1);
      a2 = fmaf(wv.z, RL(vh, 4 * j4 + 2), a2);
      a3 = fmaf(wv.w, RL(vh, 4 * j4 + 3), a3);
    }
    part[buf][w][l] = (a0 + a1) + (a2 + a3);
    __syncthreads();

    if (w == 0) {
      float s = 0.f;
#pragma unroll
      for (int q = 0; q < 8; ++q) s += part[buf][q][l];
      float xv = s + pv;
      // fast tanh: 1 - 2/(e^{2x}+1), clamped
      xv = fminf(fmaxf(xv, -15.f), 15.f);
      float e = __expf(2.f * xv);
      float hn = 1.f - 2.f / (e + 1.f);
      // Publish: relaxed agent-scope store (write-through to L3). The value
      // itself is the ready signal — no flag, no fence, no waitcnt.
      __hip_atomic_store(&h_hist[(size_t)(t + 1) * HSZ + (g << 6) + l], hn,
                         __ATOMIC_RELAXED, __HIP_MEMORY_SCOPE_AGENT);
    }
    // Double-buffered part[] makes a trailing barrier unnecessary (a wave can
    // only reach iteration t+2's part[buf] write after passing t+1's barrier).
  }
#undef RL
}

// ---------------------------------------------------------------------------
extern "C" void kernel_launch(void* const* d_in, const int* in_sizes, int n_in,
                              void* d_out, int out_size, void* d_ws, size_t ws_size,
                              hipStream_t stream) {
  const float* x  = (const float*)d_in[0];  // [SEQ][ISZ]
  const float* Wx = (const float*)d_in[1];  // [HSZ][ISZ]
  const float* Wh = (const float*)d_in[2];  // [HSZ][HSZ]
  const float* Wy = (const float*)d_in[3];  // [OSZ][HSZ]
  const float* bh = (const float*)d_in[4];  // [HSZ]
  const float* by = (const float*)d_in[5];  // [OSZ]
  float* out = (float*)d_out;               // [SEQ][OSZ]

  float* P      = (float*)d_ws;             // SEQ*HSZ      (64 MB)
  float* h_hist = P + (size_t)SEQ * HSZ;    // (SEQ+1)*HSZ  (64 MB)

  // Sentinel-fill h_hist rows 1..SEQ (NaN bits), then zero row 0 (= h_0).
  hipMemsetD32Async((hipDeviceptr_t)h_hist, (int)SENT,
                    (size_t)(SEQ + 1) * HSZ, stream);
  hipMemsetAsync(h_hist, 0, HSZ * sizeof(float), stream);

  // Phase 1: P = x @ Wx^T + bh
  gemm_bt_bias<<<dim3(SEQ / 64, HSZ / 64), dim3(256), 0, stream>>>(
      x, Wx, bh, P, SEQ, HSZ, ISZ);

  // Phase 2: sequential recurrence (persistent, 8 co-resident WGs)
  rnn_recur<<<dim3(GWG), dim3(RTHREADS), 0, stream>>>(P, Wh, h_hist);

  // Phase 3: y = h_hist[1..] @ Wy^T + by
  gemm_bt_bias<<<dim3(SEQ / 64, OSZ / 64), dim3(256), 0, stream>>>(
      h_hist + HSZ, Wy, by, out, SEQ, OSZ, HSZ);
}